// Round 13
// baseline (15500.270 us; speedup 1.0000x reference)
//
#include <hip/hip_runtime.h>
#include <math.h>

#define T_SEQ 4096
#define I_DIM 1024
#define H_DIM 2048
#define O_DIM 512
#define G4    8192   // 4*H

// ---------------------------------------------------------------------------
// Phase 1: xg[t, perm(r)] = sum_k input[t,k]*W_ih[r,k] + b_ih[r] + b_hh[r]
// perm(r): r = g*2048 + 8*q + j  ->  t*8192 + q*32 + g*8 + j
// ---------------------------------------------------------------------------
__global__ __launch_bounds__(256) void gemm_xg(
    const float* __restrict__ A, const float* __restrict__ W,
    const float* __restrict__ b_ih, const float* __restrict__ b_hh,
    float* __restrict__ xg)
{
  __shared__ __align__(16) float As[16][132];
  __shared__ __align__(16) float Bs[16][132];
  const int tid = threadIdx.x;
  const int t0 = blockIdx.y * 128;
  const int r0 = blockIdx.x * 128;
  const int tx = tid & 15, ty = tid >> 4;

  float acc[8][8];
  #pragma unroll
  for (int i = 0; i < 8; ++i)
    #pragma unroll
    for (int j = 0; j < 8; ++j) acc[i][j] = 0.f;

  for (int k0 = 0; k0 < I_DIM; k0 += 16) {
    #pragma unroll
    for (int i = 0; i < 2; ++i) {
      int lin = tid + i * 256;     // 0..511
      int row = lin >> 2;          // 0..127
      int kq  = (lin & 3) << 2;    // 0,4,8,12
      float4 va = *(const float4*)&A[(size_t)(t0 + row) * I_DIM + k0 + kq];
      As[kq+0][row] = va.x; As[kq+1][row] = va.y; As[kq+2][row] = va.z; As[kq+3][row] = va.w;
      float4 vb = *(const float4*)&W[(size_t)(r0 + row) * I_DIM + k0 + kq];
      Bs[kq+0][row] = vb.x; Bs[kq+1][row] = vb.y; Bs[kq+2][row] = vb.z; Bs[kq+3][row] = vb.w;
    }
    __syncthreads();
    #pragma unroll
    for (int kk = 0; kk < 16; ++kk) {
      float4 a0 = *(const float4*)&As[kk][ty*8];
      float4 a1 = *(const float4*)&As[kk][ty*8+4];
      float4 b0 = *(const float4*)&Bs[kk][tx*8];
      float4 b1 = *(const float4*)&Bs[kk][tx*8+4];
      float av[8] = {a0.x,a0.y,a0.z,a0.w,a1.x,a1.y,a1.z,a1.w};
      float bv[8] = {b0.x,b0.y,b0.z,b0.w,b1.x,b1.y,b1.z,b1.w};
      #pragma unroll
      for (int i = 0; i < 8; ++i)
        #pragma unroll
        for (int j = 0; j < 8; ++j)
          acc[i][j] = fmaf(av[i], bv[j], acc[i][j]);
    }
    __syncthreads();
  }

  const int rbase = r0 + tx * 8;
  const int g = rbase >> 11;
  const int q = (rbase & 2047) >> 3;
  float bias[8];
  #pragma unroll
  for (int j = 0; j < 8; ++j) bias[j] = b_ih[rbase + j] + b_hh[rbase + j];
  #pragma unroll
  for (int i = 0; i < 8; ++i) {
    int t = t0 + ty * 8 + i;
    float* dst = &xg[(size_t)t * G4 + q * 32 + g * 8];
    float4 o0 = make_float4(acc[i][0]+bias[0], acc[i][1]+bias[1], acc[i][2]+bias[2], acc[i][3]+bias[3]);
    float4 o1 = make_float4(acc[i][4]+bias[4], acc[i][5]+bias[5], acc[i][6]+bias[6], acc[i][7]+bias[7]);
    *(float4*)&dst[0] = o0;
    *(float4*)&dst[4] = o1;
  }
}

__device__ __forceinline__ float sigf(float x) {
  return 1.f / (1.f + __expf(-x));
}
__device__ __forceinline__ float tanh_fast(float x) {
  return 1.f - 2.f / (__expf(2.f * x) + 1.f);
}
__device__ __forceinline__ unsigned bf16rne(float f) {
  unsigned u = __float_as_uint(f);
  return (u + 0x7fffu + ((u >> 16) & 1u)) >> 16;
}

// ---------------------------------------------------------------------------
// Phase 2: r5 sync (self-announcing (value,tag) pairs, NREP replicas, one
// barrier/step) + weights in LDS as packed bf16.
// Rounds 8-12 lesson: per-thread VGPR weight residency is unwinnable from
// source (RA spills 256B/thread of loop-carried state every time; VGPR
// stuck at 88; weights re-streamed from L2/LLC/scratch each step = the
// ~2.6us/step floor). LDS can't be spilled: 32 rows x 1024 packed-bf16
// pairs = 128 KB weights + 16 KB h dbuf = 144 KB <= 160 KB/CU. Filled
// ONCE from W_hh (inline RNE convert), then per-step weight traffic is
// pure ds_read_b128 (~24/thread ~ 0.2-0.3us), zero cache-fabric load.
// bf16 accuracy verified in r12: absmax 4.9e-4 << 3.36e-3 threshold.
// ---------------------------------------------------------------------------
__global__ __launch_bounds__(512, 1) void lstm_seq_lds(
    const float* __restrict__ W_hh, const float* __restrict__ xg,
    uint2* __restrict__ hbuf, int nrep)
{
  __shared__ __align__(16) unsigned wlds[32][1024];  // 128 KB: row g*8+e
  __shared__ __align__(16) float    hsh[2][2048];    //  16 KB: h dbuf

  const int tid  = threadIdx.x;
  const int b    = blockIdx.x;     // 0..255
  const int lane = tid & 63;
  const int w    = tid >> 6;       // wave id = h element index within block
  const int pstr = nrep << 11;
  const int myrep = b & (nrep - 1);

  // ---- one-time LDS weight fill: row rr = g*8+e, 16 threads per row ----
  {
    const int rr = tid >> 4;        // 0..31
    const int ch = tid & 15;        // 0..15 -> pairs [ch*64, ch*64+64)
    const int g = rr >> 3, e = rr & 7;
    const float* src = &W_hh[(size_t)(g * H_DIM + 8 * b + e) * H_DIM + ch * 128];
    #pragma unroll
    for (int i = 0; i < 16; ++i) {
      float4 a = *(const float4*)&src[8 * i];
      float4 c = *(const float4*)&src[8 * i + 4];
      uint4 p;
      p.x = bf16rne(a.x) | (bf16rne(a.y) << 16);
      p.y = bf16rne(a.z) | (bf16rne(a.w) << 16);
      p.z = bf16rne(c.x) | (bf16rne(c.y) << 16);
      p.w = bf16rne(c.z) | (bf16rne(c.w) << 16);
      *(uint4*)&wlds[rr][ch * 64 + 4 * i] = p;
    }
  }
  __syncthreads();

  float c_reg = 0.f;          // cell state (lane 0 of each wave)
  bool gaveup = false;

  const float* xp0 = &xg[(size_t)0 * G4 + b * 32 + w];
  float xgi = xp0[0], xgf = xp0[8], xgg = xp0[16], xgo = xp0[24];

  for (int t = 0; t < T_SEQ; ++t) {
    const uint2* hb = hbuf + (t & 1) * pstr + (myrep << 11);
    const unsigned tag = (unsigned)t;

    // 1) poll my 4 pairs until all tags == t (the poll IS the h read)
    const uint2* a0 = hb + 256 * w + 4 * lane;
    uint4 f0, f1;
    int tries = 0;
    for (;;) {
      asm volatile("global_load_dwordx4 %0, %2, off sc0 sc1\n\t"
                   "global_load_dwordx4 %1, %3, off sc0 sc1\n\t"
                   "s_waitcnt vmcnt(0)"
                   : "=&v"(f0), "=&v"(f1)
                   : "v"(a0), "v"(a0 + 2)
                   : "memory");
      bool ok = (f0.y == tag) & (f0.w == tag) & (f1.y == tag) & (f1.w == tag);
      if (__all(ok) || gaveup) break;
      if (++tries > (1 << 17)) { gaveup = true; break; }
    }

    // 2) broadcast values into this step's LDS h buffer
    float* hd = hsh[t & 1];
    float4 hv4 = make_float4(__uint_as_float(f0.x), __uint_as_float(f0.z),
                             __uint_as_float(f1.x), __uint_as_float(f1.z));
    *(float4*)&hd[256 * w + 4 * lane] = hv4;

    // prefetch xg for t+1 (off the critical path)
    float nxi = 0.f, nxf = 0.f, nxg = 0.f, nxo = 0.f;
    if (t + 1 < T_SEQ) {
      const float* xp = &xg[(size_t)(t + 1) * G4 + b * 32 + w];
      nxi = xp[0]; nxf = xp[8]; nxg = xp[16]; nxo = xp[24];
    }

    __syncthreads();   // the ONE barrier per step

    // 3) dot: 4 gate rows x 32 cols/lane; weights from LDS (b128 reads),
    //    cols 8*lane + 512*k + [0..7], k = 0..3
    float s0 = 0.f, s1 = 0.f, s2 = 0.f, s3 = 0.f;
#define DOTG(S, G, K) { \
    uint4 u = *(const uint4*)&wlds[G * 8 + w][4 * lane + 256 * K]; \
    S = fmaf(__uint_as_float(u.x << 16),        ha.x, S); \
    S = fmaf(__uint_as_float(u.x & 0xffff0000u), ha.y, S); \
    S = fmaf(__uint_as_float(u.y << 16),        ha.z, S); \
    S = fmaf(__uint_as_float(u.y & 0xffff0000u), ha.w, S); \
    S = fmaf(__uint_as_float(u.z << 16),        hc.x, S); \
    S = fmaf(__uint_as_float(u.z & 0xffff0000u), hc.y, S); \
    S = fmaf(__uint_as_float(u.w << 16),        hc.z, S); \
    S = fmaf(__uint_as_float(u.w & 0xffff0000u), hc.w, S); }
#define DOTK(K) { \
    float4 ha = *(const float4*)&hd[8 * lane + 512 * K]; \
    float4 hc = *(const float4*)&hd[8 * lane + 512 * K + 4]; \
    DOTG(s0, 0, K) DOTG(s1, 1, K) DOTG(s2, 2, K) DOTG(s3, 3, K) }
    DOTK(0) DOTK(1) DOTK(2) DOTK(3)

    // butterfly reduce 4 values across 64 lanes
    #pragma unroll
    for (int sh = 32; sh >= 1; sh >>= 1) {
      s0 += __shfl_xor(s0, sh, 64);
      s1 += __shfl_xor(s1, sh, 64);
      s2 += __shfl_xor(s2, sh, 64);
      s3 += __shfl_xor(s3, sh, 64);
    }

    // 4) lane 0: gate math + nrep packed (value, tag) stores
    if (lane == 0) {
      float iv = sigf(s0 + xgi);
      float fv = sigf(s1 + xgf);
      float gv = tanh_fast(s2 + xgg);
      float ov = sigf(s3 + xgo);
      c_reg = fv * c_reg + iv * gv;
      float hv = ov * tanh_fast(c_reg);
      uint2 pv;
      pv.x = __float_as_uint(hv);
      pv.y = (unsigned)(t + 1);
      uint2* dst = hbuf + ((t + 1) & 1) * pstr + 8 * b + w;
      for (int r = 0; r < nrep; ++r) {
        asm volatile("global_store_dwordx2 %0, %1, off sc0 sc1"
                     :: "v"(dst), "v"(pv) : "memory");
        dst += 2048;
      }
    }

    xgi = nxi; xgf = nxf; xgg = nxg; xgo = nxo;
  }
}

// ---------------------------------------------------------------------------
// Phase 3: out[o] = h_last . W_lin[o,:] + b_lin[o]. One wave per output.
// h_last = values of replica-0 pairs at parity 0 (step 4095 writes par 0).
// ---------------------------------------------------------------------------
__global__ __launch_bounds__(256) void proj_out(
    const float* __restrict__ W_lin, const float* __restrict__ b_lin,
    const uint2* __restrict__ hpairs, float* __restrict__ out)
{
  const int tid = threadIdx.x;
  const int lane = tid & 63;
  const int w4 = tid >> 6;
  const int o = blockIdx.x * 4 + w4;
  const float* wr = &W_lin[(size_t)o * H_DIM + 4 * lane];
  float s = 0.f;
  #pragma unroll
  for (int k = 0; k < 8; ++k) {
    float4 wv = *(const float4*)&wr[256 * k];
    uint4 p0 = *(const uint4*)&hpairs[4 * lane + 256 * k];
    uint4 p1 = *(const uint4*)&hpairs[4 * lane + 256 * k + 2];
    s = fmaf(wv.x, __uint_as_float(p0.x), s);
    s = fmaf(wv.y, __uint_as_float(p0.z), s);
    s = fmaf(wv.z, __uint_as_float(p1.x), s);
    s = fmaf(wv.w, __uint_as_float(p1.z), s);
  }
  #pragma unroll
  for (int sh = 32; sh >= 1; sh >>= 1) s += __shfl_xor(s, sh, 64);
  if (lane == 0) out[o] = s + b_lin[o];
}

// ---------------------------------------------------------------------------
extern "C" void kernel_launch(void* const* d_in, const int* in_sizes, int n_in,
                              void* d_out, int out_size, void* d_ws, size_t ws_size,
                              hipStream_t stream)
{
  const float* input = (const float*)d_in[0];
  const float* W_ih  = (const float*)d_in[1];
  const float* W_hh  = (const float*)d_in[2];
  const float* b_ih  = (const float*)d_in[3];
  const float* b_hh  = (const float*)d_in[4];
  const float* W_lin = (const float*)d_in[5];
  const float* b_lin = (const float*)d_in[6];
  float* out = (float*)d_out;

  char* ws = (char*)d_ws;
  const size_t XG_BYTES = (size_t)T_SEQ * G4 * sizeof(float);   // 128 MB
  const size_t HB8      = 2ull * 8 * H_DIM * sizeof(uint2);     // 256 KB
  float* xg   = (float*)ws;
  uint2* hbuf = (uint2*)(ws + XG_BYTES);

  int nrep = (ws_size >= XG_BYTES + HB8) ? 8 : 1;
  const size_t HB_BYTES = 2ull * nrep * H_DIM * sizeof(uint2);

  // zero pair buffers: h_0 = 0 with tag 0 (= step-0 poll target)
  (void)hipMemsetAsync(ws + XG_BYTES, 0, HB_BYTES, stream);

  gemm_xg<<<dim3(64, 32), 256, 0, stream>>>(input, W_ih, b_ih, b_hh, xg);
  lstm_seq_lds<<<256, 512, 0, stream>>>(W_hh, xg, hbuf, nrep);
  proj_out<<<128, 256, 0, stream>>>(W_lin, b_lin, hbuf, out);
}